// Round 1
// 3372.581 us; speedup vs baseline: 1.1552x; 1.1552x over previous
//
#include <hip/hip_runtime.h>
#include <math.h>

// Problem constants (fixed by the reference)
#define BATCH   2
#define NQ_CB   4
#define T_SEQ   1024
#define DMODEL  1024
#define NHEAD   16
#define HDIM    64
#define NLAYER  8
#define CARD_SZ 1024
#define NCOND   64
#define CONDD   768
#define DFF_SZ  4096
#define WIN     5

typedef __attribute__((ext_vector_type(8))) short bf16x8;
typedef __attribute__((ext_vector_type(4))) float f32x4;
typedef unsigned short ushortx;

// float -> bf16 (RNE) raw bits
__device__ inline short f2bf(float f) {
  union { float f; unsigned u; } c;
  c.f = f;
  unsigned r = (c.u + 0x7FFFu + ((c.u >> 16) & 1u)) >> 16;
  return (short)r;
}
// bf16 raw bits -> float
__device__ inline float bf2f(unsigned short u) {
  union { unsigned u; float f; } c;
  c.u = ((unsigned)u) << 16;
  return c.f;
}

// async global->LDS, 16B per lane; lds dest = wave-uniform base + lane*16
__device__ inline void gld_lds16(const void* g, void* s) {
  __builtin_amdgcn_global_load_lds(
      (const __attribute__((address_space(1))) void*)g,
      (__attribute__((address_space(3))) void*)s, 16, 0, 0);
}

// counted vmcnt wait (T4): never drain to 0 in steady state
template <int N> __device__ inline void s_wait_vmcnt() {
  asm volatile("s_waitcnt vmcnt(%0)" :: "n"(N) : "memory");
}

// raw barrier with compiler memory fences (cheap; prevents LDS reordering)
__device__ inline void blk_bar() {
  asm volatile("" ::: "memory");
  __builtin_amdgcn_s_barrier();
  asm volatile("" ::: "memory");
}

// ---------------------------------------------------------------------------
// Weight pack: fp32 (K,N) row-major -> bf16 fragment-layout slabs.
// slab (ng, kt) = 512 shorts; element (k,n):
//   dst[(ng*KT + kt)*512 + ((n&15)|(((k>>3)&3)<<4))*8 + (k&7)] ; ng=n>>4, kt=k>>5
// grid.z = matrix index in a (z,K,N) stack.
// ---------------------------------------------------------------------------
__global__ __launch_bounds__(256) void pack_kernel(
    const float* __restrict__ src, short* __restrict__ dst, int K, int N)
{
  size_t matoff = (size_t)blockIdx.z * K * N;
  src += matoff; dst += matoff;
  int gid = blockIdx.x * 256 + threadIdx.x;   // one bf16x8 cell per thread
  int slab = gid >> 6, cell = gid & 63;
  int KT = K >> 5;
  int ng = slab / KT, kt = slab - ng * KT;
  int n = ng * 16 + (cell & 15);
  int k = kt * 32 + (cell >> 4) * 8;
  bf16x8 pk;
#pragma unroll
  for (int j = 0; j < 8; ++j) pk[j] = f2bf(src[(size_t)(k + j) * N + n]);
  *(bf16x8*)&dst[(size_t)gid * 8] = pk;
}

// ---------------------------------------------------------------------------
// Embedding sum + sinusoidal positional embedding -> h (fp32)
// ---------------------------------------------------------------------------
__global__ __launch_bounds__(256) void embed_kernel(
    const int* __restrict__ x, const float* __restrict__ emb,
    float* __restrict__ h)
{
  int bt = blockIdx.x;
  int b = bt >> 10, t = bt & (T_SEQ - 1);
  int tid = threadIdx.x;
  float4 acc = make_float4(0.f, 0.f, 0.f, 0.f);
#pragma unroll
  for (int q = 0; q < NQ_CB; ++q) {
    int idx = x[(b * NQ_CB + q) * T_SEQ + t];
    const float4* er =
        (const float4*)(emb + ((size_t)q * (CARD_SZ + 1) + idx) * DMODEL);
    float4 e = er[tid];
    acc.x += e.x; acc.y += e.y; acc.z += e.z; acc.w += e.w;
  }
  int d0 = tid * 4;
  float c = -logf(10000.f) * (2.f / (float)DMODEL);
  float th0 = (float)t * expf(c * (float)(d0 >> 1));
  float th1 = (float)t * expf(c * (float)((d0 + 2) >> 1));
  acc.x += sinf(th0); acc.y += cosf(th0);
  acc.z += sinf(th1); acc.w += cosf(th1);
  ((float4*)(h + (size_t)bt * DMODEL))[tid] = acc;
}

// ---------------------------------------------------------------------------
// LayerNorm (fp32 in, bf16 out). One block per row.
// ---------------------------------------------------------------------------
__global__ __launch_bounds__(256) void ln_kernel(
    const float* __restrict__ x, const float* __restrict__ g,
    const float* __restrict__ b, ushortx* __restrict__ y)
{
  int row = blockIdx.x;
  int tid = threadIdx.x;
  const float4* xr = (const float4*)(x + (size_t)row * DMODEL);
  float4 v = xr[tid];
  float s  = v.x + v.y + v.z + v.w;
  float ss = v.x * v.x + v.y * v.y + v.z * v.z + v.w * v.w;
#pragma unroll
  for (int off = 32; off; off >>= 1) {
    s  += __shfl_xor(s, off, 64);
    ss += __shfl_xor(ss, off, 64);
  }
  __shared__ float sh_s[4], sh_ss[4];
  int w = tid >> 6;
  if ((tid & 63) == 0) { sh_s[w] = s; sh_ss[w] = ss; }
  __syncthreads();
  s  = sh_s[0] + sh_s[1] + sh_s[2] + sh_s[3];
  ss = sh_ss[0] + sh_ss[1] + sh_ss[2] + sh_ss[3];
  float mean = s * (1.f / DMODEL);
  float var  = ss * (1.f / DMODEL) - mean * mean;
  float rstd = rsqrtf(var + 1e-5f);
  float4 gv = ((const float4*)g)[tid];
  float4 bv = ((const float4*)b)[tid];
  ushort4 o;
  o.x = (ushortx)f2bf((v.x - mean) * rstd * gv.x + bv.x);
  o.y = (ushortx)f2bf((v.y - mean) * rstd * gv.y + bv.y);
  o.z = (ushortx)f2bf((v.z - mean) * rstd * gv.z + bv.z);
  o.w = (ushortx)f2bf((v.w - mean) * rstd * gv.w + bv.w);
  *(ushort4*)(y + (size_t)row * DMODEL + tid * 4) = o;
}

// ---------------------------------------------------------------------------
// bf16 MFMA GEMM, packed-B via global_load_lds, double-buffered pipeline.
// A: bf16 row-major (ABF16=1, DMA-staged) or fp32 row-major (ABF16=0, MW==2).
// Wp*: packed bf16 weights (layout above). Tile BMx128, BK=64, 4 waves 2x2.
// Pipeline (T3 minimum 2-phase): stage(kt+1) issued before compute(kt);
// counted vmcnt (T4) keeps next-tile loads in flight across the barrier.
// z decode: w = z%nw selects {W,b,C}; li = z/nw steps strides / head remap.
// flags: 1=gelu, 2=head_remap(li = codebook), 4=out bf16.
// ---------------------------------------------------------------------------
#define FL_GELU  1
#define FL_REMAP 2
#define FL_OBF16 4

template <int MW, int ABF16>
__global__ __launch_bounds__(256, 2) void gemm_pk(
    const void* __restrict__ Ain,
    const short* __restrict__ Wp0, const short* __restrict__ Wp1,
    const short* __restrict__ Wp2, long wstride, int nw,
    const float* __restrict__ b0, const float* __restrict__ b1,
    const float* __restrict__ b2, long bstride,
    const float* __restrict__ resid,
    void* __restrict__ C0v, void* __restrict__ C1v, void* __restrict__ C2v,
    long cstride,
    int M, int N, int K, int flags)
{
  // double-buffered tiles: A = BM x 64, B = 128 x 64 (bf16), slab = 512 shorts
  __shared__ __align__(16) short Als[2][MW * 2048];   // (BM/16)*2 slabs per buf
  __shared__ __align__(16) short Bls[2][8192];        // 16 slabs per buf

  int tid = threadIdx.x;
  int z = blockIdx.z;
  int w = z % nw, li = z / nw;
  const short* Wp = (w == 0 ? Wp0 : (w == 1 ? Wp1 : Wp2)) + (size_t)li * wstride;
  const float* bias = (w == 0 ? b0 : (w == 1 ? b1 : b2)) + (size_t)li * bstride;
  char* Cb = (char*)(w == 0 ? C0v : (w == 1 ? C1v : C2v)) + (size_t)li * cstride;

  int bm = blockIdx.y * (MW * 32);
  int bn = blockIdx.x * 128;
  int wave = tid >> 6, lane = tid & 63;
  int wm = (wave >> 1) * (MW * 16);
  int wn = (wave & 1) * 64;
  int KT = K >> 5;                 // number of 32-k slabs
  const int NT = K >> 6;           // number of BK=64 steps
  constexpr int NSTG = 4 + (ABF16 ? MW : 0);  // gld_lds per wave per stage

  f32x4 acc[MW][4];
#pragma unroll
  for (int i = 0; i < MW; ++i)
#pragma unroll
    for (int j = 0; j < 4; ++j) {
      acc[i][j][0] = 0.f; acc[i][j][1] = 0.f;
      acc[i][j][2] = 0.f; acc[i][j][3] = 0.f;
    }

  auto stage = [&](int kt, int buf) {
    // ---- B: 16 slabs of 1KB via DMA (4 per wave) ----
#pragma unroll
    for (int i = 0; i < 4; ++i) {
      int s = wave * 4 + i;            // slab id = ng*2 + ks
      const short* src =
          Wp + ((size_t)((bn >> 4) + (s >> 1)) * KT + 2 * kt + (s & 1)) * 512 +
          lane * 8;
      gld_lds16(src, &Bls[buf][s * 512]);
    }
    // ---- A ----
    if (ABF16) {
      const ushortx* A16 = (const ushortx*)Ain;
#pragma unroll
      for (int i = 0; i < MW; ++i) {
        int s = wave * MW + i;         // slab id = mg*2 + ks
        const ushortx* src = A16 +
            (size_t)(bm + (s >> 1) * 16 + (lane & 15)) * K +
            kt * 64 + (s & 1) * 32 + (lane >> 4) * 8;
        gld_lds16(src, &Als[buf][s * 512]);
      }
    } else {  // fp32 A register staging (MW==2 only; used for cond K/V)
      const float* Af = (const float*)Ain;
      int m = tid >> 2, kq = tid & 3;
#pragma unroll
      for (int ks = 0; ks < 2; ++ks) {
        const float* src = Af + (size_t)(bm + m) * K + kt * 64 + ks * 32 + kq * 8;
        float4 f0 = *(const float4*)src;
        float4 f1 = *(const float4*)(src + 4);
        bf16x8 pk;
        pk[0] = f2bf(f0.x); pk[1] = f2bf(f0.y); pk[2] = f2bf(f0.z); pk[3] = f2bf(f0.w);
        pk[4] = f2bf(f1.x); pk[5] = f2bf(f1.y); pk[6] = f2bf(f1.z); pk[7] = f2bf(f1.w);
        *(bf16x8*)&Als[buf][((m >> 4) * 2 + ks) * 512 + ((m & 15) | (kq << 4)) * 8] = pk;
      }
    }
  };

  // prologue: stage tile 0 into buffer 0
  stage(0, 0);
  int cur = 0;

  for (int kt = 0; kt < NT; ++kt) {
    // issue next tile's loads into the other buffer BEFORE computing this one
    if (kt + 1 < NT) {
      stage(kt + 1, cur ^ 1);
      if (ABF16) s_wait_vmcnt<NSTG>();   // wait for tile kt only; kt+1 in flight
      else       s_wait_vmcnt<0>();      // fp32 path: conservative (tiny GEMM)
    } else {
      s_wait_vmcnt<0>();                 // drain last tile
    }
    if (!ABF16) asm volatile("s_waitcnt lgkmcnt(0)" ::: "memory");
    blk_bar();                           // buf[cur] fully staged for all waves

    // ---- compute on buf[cur]: BK=64 = two 32-k sub-steps ----
#pragma unroll
    for (int ks = 0; ks < 2; ++ks) {
      bf16x8 af[MW], bfr[4];
#pragma unroll
      for (int i = 0; i < MW; ++i)
        af[i] = *(bf16x8*)&Als[cur][(((wm >> 4) + i) * 2 + ks) * 512 + lane * 8];
#pragma unroll
      for (int j = 0; j < 4; ++j)
        bfr[j] = *(bf16x8*)&Bls[cur][(((wn >> 4) + j) * 2 + ks) * 512 + lane * 8];
#pragma unroll
      for (int i = 0; i < MW; ++i)
#pragma unroll
        for (int j = 0; j < 4; ++j)
          acc[i][j] = __builtin_amdgcn_mfma_f32_16x16x32_bf16(
              af[i], bfr[j], acc[i][j], 0, 0, 0);
    }
    blk_bar();                           // all reads of buf[cur] done -> reusable
    cur ^= 1;
  }

  // ---- epilogue (C/D layout: col=lane&15, row=quad*4+reg) ----
  int quad = lane >> 4, col = lane & 15;
#pragma unroll
  for (int i = 0; i < MW; ++i) {
    int m0 = bm + wm + i * 16 + quad * 4;
#pragma unroll
    for (int j = 0; j < 4; ++j) {
      int n0 = bn + wn + j * 16 + col;
      float bval = bias[n0];
#pragma unroll
      for (int r = 0; r < 4; ++r) {
        int m = m0 + r;
        float v = acc[i][j][r] + bval;
        if (flags & FL_GELU) {
          v = 0.5f * v *
              (1.f + tanhf(0.7978845608028654f * (v + 0.044715f * v * v * v)));
        }
        if (resid) v += resid[(size_t)m * N + n0];
        size_t row;
        if (flags & FL_REMAP)
          row = ((size_t)(m >> 10) * NQ_CB + li) * T_SEQ + (m & (T_SEQ - 1));
        else
          row = m;
        if (flags & FL_OBF16)
          ((ushortx*)Cb)[row * N + n0] = (ushortx)f2bf(v);
        else
          ((float*)Cb)[row * N + n0] = v;
      }
    }
  }
}

// ---------------------------------------------------------------------------
// Banded self-attention (WIN=5, 11 keys). One wave per (b,h,t). bf16 I/O.
// ---------------------------------------------------------------------------
__global__ __launch_bounds__(256) void self_attn_kernel(
    const ushortx* __restrict__ q, const ushortx* __restrict__ k,
    const ushortx* __restrict__ v, ushortx* __restrict__ o)
{
  int w = blockIdx.x * 4 + (threadIdx.x >> 6);
  int lane = threadIdx.x & 63;
  int t = w & (T_SEQ - 1);
  int bh = w >> 10;
  int h = bh & (NHEAD - 1);
  int b = bh >> 4;
  size_t base = ((size_t)(b * T_SEQ) * DMODEL) + h * HDIM + lane;
  float qv = bf2f(q[base + (size_t)t * DMODEL]);

  float sc[2 * WIN + 1];
  float mx = -1e30f;
#pragma unroll
  for (int j = 0; j < 2 * WIN + 1; ++j) {
    int s = t - WIN + j;
    float d;
    if (s >= 0 && s < T_SEQ) {
      float kv = bf2f(k[base + (size_t)s * DMODEL]);
      d = qv * kv;
#pragma unroll
      for (int off = 32; off; off >>= 1) d += __shfl_xor(d, off, 64);
      d *= 0.125f;
    } else {
      d = -1e30f;
    }
    sc[j] = d;
    mx = fmaxf(mx, d);
  }
  float sum = 0.f;
#pragma unroll
  for (int j = 0; j < 2 * WIN + 1; ++j) {
    sc[j] = expf(sc[j] - mx);
    sum += sc[j];
  }
  float inv = 1.f / sum;
  float ov = 0.f;
#pragma unroll
  for (int j = 0; j < 2 * WIN + 1; ++j) {
    int s = t - WIN + j;
    if (s >= 0 && s < T_SEQ) ov += sc[j] * bf2f(v[base + (size_t)s * DMODEL]);
  }
  o[base + (size_t)t * DMODEL] = (ushortx)f2bf(ov * inv);
}

// ---------------------------------------------------------------------------
// Cross-attention over NCOND=64 keys. One wave per (b,h,t). bf16 I/O.
// ---------------------------------------------------------------------------
__global__ __launch_bounds__(256) void cross_attn_kernel(
    const ushortx* __restrict__ q, const ushortx* __restrict__ k,
    const ushortx* __restrict__ v, ushortx* __restrict__ o)
{
  int w = blockIdx.x * 4 + (threadIdx.x >> 6);
  int lane = threadIdx.x & 63;
  int t = w & (T_SEQ - 1);
  int h = (w >> 10) & (NHEAD - 1);
  int b = w >> 14;
  size_t qoff = ((size_t)(b * T_SEQ + t) * DMODEL) + h * HDIM;
  float qv = bf2f(q[qoff + lane]);

  const ushortx* krow = k + ((size_t)(b * NCOND + lane) * DMODEL) + h * HDIM;
  float s_l = 0.f;
#pragma unroll
  for (int d = 0; d < HDIM; ++d) {
    float qd = __shfl(qv, d, 64);
    s_l += qd * bf2f(krow[d]);
  }
  s_l *= 0.125f;
  float m = s_l;
#pragma unroll
  for (int off = 32; off; off >>= 1) m = fmaxf(m, __shfl_xor(m, off, 64));
  float p = expf(s_l - m);
  float sum = p;
#pragma unroll
  for (int off = 32; off; off >>= 1) sum += __shfl_xor(sum, off, 64);
  p /= sum;

  float ov = 0.f;
  const ushortx* vb = v + ((size_t)(b * NCOND) * DMODEL) + h * HDIM + lane;
#pragma unroll
  for (int s = 0; s < NCOND; ++s) {
    float ps = __shfl(p, s, 64);
    ov += ps * bf2f(vb[(size_t)s * DMODEL]);
  }
  o[qoff + lane] = (ushortx)f2bf(ov);
}

// ---------------------------------------------------------------------------
// Host side
// ---------------------------------------------------------------------------
static void gemm_launch(hipStream_t st, int MW, int abf16,
    const void* A, const short* W0, const short* W1, const short* W2,
    long wstride, int nw,
    const float* b0, const float* b1, const float* b2, long bstride,
    const float* resid, void* C0, void* C1, void* C2, long cstride,
    int M, int N, int K, int z, int flags)
{
  dim3 grid(N / 128, M / (MW * 32), z);
  if (MW == 4)
    hipLaunchKernelGGL((gemm_pk<4, 1>), grid, dim3(256), 0, st, A, W0, W1, W2,
                       wstride, nw, b0, b1, b2, bstride, resid, C0, C1, C2,
                       cstride, M, N, K, flags);
  else if (abf16)
    hipLaunchKernelGGL((gemm_pk<2, 1>), grid, dim3(256), 0, st, A, W0, W1, W2,
                       wstride, nw, b0, b1, b2, bstride, resid, C0, C1, C2,
                       cstride, M, N, K, flags);
  else
    hipLaunchKernelGGL((gemm_pk<2, 0>), grid, dim3(256), 0, st, A, W0, W1, W2,
                       wstride, nw, b0, b1, b2, bstride, resid, C0, C1, C2,
                       cstride, M, N, K, flags);
}

extern "C" void kernel_launch(void* const* d_in, const int* in_sizes, int n_in,
                              void* d_out, int out_size, void* d_ws, size_t ws_size,
                              hipStream_t stream)
{
  const int*   x     = (const int*)  d_in[0];
  const float* cond  = (const float*)d_in[1];
  const float* emb   = (const float*)d_in[2];
  const float* ln1_g = (const float*)d_in[3];
  const float* ln1_b = (const float*)d_in[4];
  const float* ln2_g = (const float*)d_in[5];
  const float* ln2_b = (const float*)d_in[6];
  const float* ln3_g = (const float*)d_in[7];
  const float* ln3_b = (const float*)d_in[8];
  const float* sWq   = (const float*)d_in[9];
  const float* sWk   = (const float*)d_in[10];
  const float* sWv   = (const float*)d_in[11];
  const float* sWo   = (const float*)d_in[12];
  const float* sbq   = (const float*)d_in[13];
  const float* sbk   = (const float*)d_in[14];
  const float* sbv   = (const float*)d_in[15];
  const float* sbo   = (const float*)d_in[16];
  const float* cWq   = (const float*)d_in[17];
  const float* cWk   = (const float*)d_in[18];
  const float* cWv   = (const float*)d_in[19];
  const float* cWo   = (const float*)d_in[20];
  const float* cbq   = (const float*)d_in[21];
  const float* cbk   = (const float*)d_in[22];
  const float* cbv   = (const float*)d_in[23];
  const float* cbo   = (const float*)d_in[24];
  const float* W1    = (const float*)d_in[25];
  const float* b1    = (const float*)d_in[26];
  const float* W2    = (const float*)d_in[27];
  const float* b2    = (const float*)d_in[28];
  const float* out_g = (const float*)d_in[29];
  const float* out_b = (const float*)d_in[30];
  const float* headW = (const float*)d_in[31];
  const float* headb = (const float*)d_in[32];

  float* out = (float*)d_out;
  const size_t MB = 1u << 20;
  const long MAT = 1048576L;           // 1024*1024
  const long CMAT = 768L * 1024;       // cWk/cWv per-layer elements
  const long FMAT = 4L * 1048576;      // W1/W2 per-layer elements
  const int M = BATCH * T_SEQ;         // 2048

  char* wsb = (char*)d_ws;
  float*   h   = (float*)(wsb);              // 8 MB fp32
  ushortx* tmp = (ushortx*)(wsb + 8 * MB);   // 4 MB bf16
  ushortx* qb  = (ushortx*)(wsb + 12 * MB);
  ushortx* kb  = (ushortx*)(wsb + 16 * MB);
  ushortx* vb  = (ushortx*)(wsb + 20 * MB);
  ushortx* ao  = (ushortx*)(wsb + 24 * MB);
  ushortx* ffn = qb;                          // 16 MB bf16, aliases qb..ao
  ushortx* ckv = (ushortx*)(wsb + 28 * MB);   // 4 MB bf16 (16 slabs 128x1024)
  short*   PB  = (short*)(wsb + 32 * MB);     // pack region

  bool big = ws_size >= (size_t)32 * MB + (size_t)268435456;

  auto pack = [&](const float* src, short* dst, int K, int N, int z) {
    hipLaunchKernelGGL(pack_kernel, dim3((unsigned)((size_t)K * N / 2048), 1, z),
                       dim3(256), 0, stream, src, dst, K, N);
  };

  // Upfront pack (big path): fixed offsets in shorts
  short *Pq = PB, *Pk = PB + 8 * MAT, *Pv = PB + 16 * MAT, *Po = PB + 24 * MAT;
  short *Pcq = PB + 32 * MAT, *Pco = PB + 40 * MAT;
  short *Pck = PB + 48 * MAT, *Pcv = PB + 54 * MAT;
  short *Pw1 = PB + 60 * MAT, *Pw2 = PB + 92 * MAT, *Phd = PB + 124 * MAT;
  if (big) {
    pack(sWq, Pq, 1024, 1024, 8);  pack(sWk, Pk, 1024, 1024, 8);
    pack(sWv, Pv, 1024, 1024, 8);  pack(sWo, Po, 1024, 1024, 8);
    pack(cWq, Pcq, 1024, 1024, 8); pack(cWo, Pco, 1024, 1024, 8);
    pack(cWk, Pck, 768, 1024, 8);  pack(cWv, Pcv, 768, 1024, 8);
    pack(W1, Pw1, 1024, 4096, 8);  pack(W2, Pw2, 4096, 1024, 8);
    pack(headW, Phd, 1024, 1024, 4);
  }

  hipLaunchKernelGGL(embed_kernel, dim3(M), dim3(256), 0, stream, x, emb, h);

  // ---- cross K/V for all layers (cond is layer-invariant) ----
  if (big) {
    gemm_launch(stream, 2, 0, cond, Pck, Pcv, nullptr, CMAT, 2,
                cbk, cbv, nullptr, 1024, nullptr,
                ckv, (char*)ckv + 262144, nullptr, 524288,
                BATCH * NCOND, DMODEL, CONDD, 16, FL_OBF16);
  } else {
    pack(cWk, PB, 768, 1024, 8);
    gemm_launch(stream, 2, 0, cond, PB, nullptr, nullptr, CMAT, 1,
                cbk, nullptr, nullptr, 1024, nullptr,
                ckv, nullptr, nullptr, 524288,
                BATCH * NCOND, DMODEL, CONDD, 8, FL_OBF16);
    pack(cWv, PB, 768, 1024, 8);
    gemm_launch(stream, 2, 0, cond, PB, nullptr, nullptr, CMAT, 1,
                cbv, nullptr, nullptr, 1024, nullptr,
                (char*)ckv + 262144, nullptr, nullptr, 524288,
                BATCH * NCOND, DMODEL, CONDD, 8, FL_OBF16);
  }

  const int attn_blocks = BATCH * NHEAD * T_SEQ / 4;

  for (int l = 0; l < NLAYER; ++l) {
    const float* L1g = ln1_g + l * DMODEL, *L1b = ln1_b + l * DMODEL;
    const float* L2g = ln2_g + l * DMODEL, *L2b = ln2_b + l * DMODEL;
    const float* L3g = ln3_g + l * DMODEL, *L3b = ln3_b + l * DMODEL;

    // --- self attention ---
    hipLaunchKernelGGL(ln_kernel, dim3(M), dim3(256), 0, stream, h, L1g, L1b, tmp);
    {
      const short *wq, *wk, *wv;
      if (big) { wq = Pq + l * MAT; wk = Pk + l * MAT; wv = Pv + l * MAT; }
      else {
        pack(sWq + (size_t)l * MAT, PB, 1024, 1024, 1);
        pack(sWk + (size_t)l * MAT, PB + MAT, 1024, 1024, 1);
        pack(sWv + (size_t)l * MAT, PB + 2 * MAT, 1024, 1024, 1);
        wq = PB; wk = PB + MAT; wv = PB + 2 * MAT;
      }
      gemm_launch(stream, 4, 1, tmp, wq, wk, wv, 0, 3,
                  sbq + l * DMODEL, sbk + l * DMODEL, sbv + l * DMODEL, 0,
                  nullptr, qb, kb, vb, 0, M, DMODEL, DMODEL, 3, FL_OBF16);
    }
    hipLaunchKernelGGL(self_attn_kernel, dim3(attn_blocks), dim3(256), 0, stream,
                       qb, kb, vb, ao);
    {
      const short* wo = big ? Po + l * MAT : PB;
      if (!big) pack(sWo + (size_t)l * MAT, PB, 1024, 1024, 1);
      gemm_launch(stream, 2, 1, ao, wo, nullptr, nullptr, 0, 1,
                  sbo + l * DMODEL, nullptr, nullptr, 0,
                  h, h, nullptr, nullptr, 0, M, DMODEL, DMODEL, 1, 0);
    }

    // --- cross attention ---
    hipLaunchKernelGGL(ln_kernel, dim3(M), dim3(256), 0, stream, h, L2g, L2b, tmp);
    {
      const short* wcq = big ? Pcq + l * MAT : PB;
      if (!big) pack(cWq + (size_t)l * MAT, PB, 1024, 1024, 1);
      gemm_launch(stream, 2, 1, tmp, wcq, nullptr, nullptr, 0, 1,
                  cbq + l * DMODEL, nullptr, nullptr, 0,
                  nullptr, qb, nullptr, nullptr, 0, M, DMODEL, DMODEL, 1, FL_OBF16);
    }
    hipLaunchKernelGGL(cross_attn_kernel, dim3(attn_blocks), dim3(256), 0, stream,
                       qb, ckv + (size_t)(2 * l) * 131072,
                       ckv + (size_t)(2 * l + 1) * 131072, ao);
    {
      const short* wco = big ? Pco + l * MAT : PB;
      if (!big) pack(cWo + (size_t)l * MAT, PB, 1024, 1024, 1);
      gemm_launch(stream, 2, 1, ao, wco, nullptr, nullptr, 0, 1,
                  cbo + l * DMODEL, nullptr, nullptr, 0,
                  h, h, nullptr, nullptr, 0, M, DMODEL, DMODEL, 1, 0);
    }

    // --- FFN ---
    hipLaunchKernelGGL(ln_kernel, dim3(M), dim3(256), 0, stream, h, L3g, L3b, tmp);
    {
      const short* w1p = big ? Pw1 + l * FMAT : PB;
      if (!big) pack(W1 + (size_t)l * FMAT, PB, 1024, 4096, 1);
      gemm_launch(stream, 4, 1, tmp, w1p, nullptr, nullptr, 0, 1,
                  b1 + l * DFF_SZ, nullptr, nullptr, 0,
                  nullptr, ffn, nullptr, nullptr, 0,
                  M, DFF_SZ, DMODEL, 1, FL_GELU | FL_OBF16);
      const short* w2p = big ? Pw2 + l * FMAT : PB;
      if (!big) pack(W2 + (size_t)l * FMAT, PB, 4096, 1024, 1);
      gemm_launch(stream, 2, 1, ffn, w2p, nullptr, nullptr, 0, 1,
                  b2 + l * DMODEL, nullptr, nullptr, 0,
                  h, h, nullptr, nullptr, 0, M, DMODEL, DFF_SZ, 1, 0);
    }
  }

  // --- output norm + heads (batched z=4, row-remapped) ---
  hipLaunchKernelGGL(ln_kernel, dim3(M), dim3(256), 0, stream, h, out_g, out_b, tmp);
  {
    const short* whd = big ? Phd : PB;
    if (!big) pack(headW, PB, 1024, 1024, 4);
    gemm_launch(stream, 4, 1, tmp, whd, nullptr, nullptr, MAT, 1,
                headb, nullptr, nullptr, CARD_SZ, nullptr,
                out, nullptr, nullptr, 0, M, CARD_SZ, DMODEL, 4, FL_REMAP);
  }
}